// Round 1
// 267.894 us; speedup vs baseline: 1.0749x; 1.0749x over previous
//
#include <hip/hip_runtime.h>
#include <hip/hip_bf16.h>

// Problem constants
#define B 8
#define H 3584
#define NH 28
#define KVH 4
#define HD 128
#define GS 7
#define MB 16
#define BS 256
#define R 32           // B*KVH
#define NCHUNK 64      // MB*BS/64 chunks of 64 tokens per row
#define SCALE 0.08838834764831845f

__device__ __forceinline__ float dot4(float4 a, float4 b) {
    return fmaf(a.x, b.x, fmaf(a.y, b.y, fmaf(a.z, b.z, a.w * b.w)));
}

// Sum across a 16-lane DPP row; every lane in the row ends with the row sum.
__device__ __forceinline__ float red16(float v) {
    v += __int_as_float(__builtin_amdgcn_update_dpp(0, __float_as_int(v), 0xB1,  0xf, 0xf, false)); // quad_perm [1,0,3,2]
    v += __int_as_float(__builtin_amdgcn_update_dpp(0, __float_as_int(v), 0x4E,  0xf, 0xf, false)); // quad_perm [2,3,0,1]
    v += __int_as_float(__builtin_amdgcn_update_dpp(0, __float_as_int(v), 0x141, 0xf, 0xf, false)); // row_half_mirror
    v += __int_as_float(__builtin_amdgcn_update_dpp(0, __float_as_int(v), 0x140, 0xf, 0xf, false)); // row_mirror
    return v;
}

// ---------------- Kernel 1: fused QKV GEMV ----------------
__global__ __launch_bounds__(256) void qkv_kernel(
    const float* __restrict__ hid,
    const float* __restrict__ qw, const float* __restrict__ qb,
    const float* __restrict__ kw, const float* __restrict__ kb,
    const float* __restrict__ vw, const float* __restrict__ vb,
    float* __restrict__ qout, float* __restrict__ kout, float* __restrict__ vout)
{
    const int blk = blockIdx.x;
    const int tid = threadIdx.x;
    const int w = tid >> 6;
    const int f0 = blk * 4;

    const float* W; const float* Bv; float* Out; int fbase; int ostr;
    if (blk < 896)       { W = qw; Bv = qb; Out = qout; fbase = f0;        ostr = 3584; }
    else if (blk < 1024) { W = kw; Bv = kb; Out = kout; fbase = f0 - 3584; ostr = 512;  }
    else                 { W = vw; Bv = vb; Out = vout; fbase = f0 - 4096; ostr = 512;  }

    const float4* wr0 = (const float4*)(W + (size_t)(fbase + 0) * H);
    const float4* wr1 = (const float4*)(W + (size_t)(fbase + 1) * H);
    const float4* wr2 = (const float4*)(W + (size_t)(fbase + 2) * H);
    const float4* wr3 = (const float4*)(W + (size_t)(fbase + 3) * H);
    const float4* h4 = (const float4*)hid;

    float acc[4][8];
    #pragma unroll
    for (int i = 0; i < 4; ++i)
        #pragma unroll
        for (int b = 0; b < 8; ++b) acc[i][b] = 0.f;

    #pragma unroll
    for (int k = 0; k < 4; ++k) {
        const int c = tid + k * 256;
        if (c < 896) {
            float4 w0 = wr0[c], w1 = wr1[c], w2 = wr2[c], w3 = wr3[c];
            float4 hb[8];
            #pragma unroll
            for (int b = 0; b < 8; ++b) hb[b] = h4[b * 896 + c];
            #pragma unroll
            for (int b = 0; b < 8; ++b) {
                acc[0][b] += dot4(w0, hb[b]);
                acc[1][b] += dot4(w1, hb[b]);
                acc[2][b] += dot4(w2, hb[b]);
                acc[3][b] += dot4(w3, hb[b]);
            }
        }
    }
    #pragma unroll
    for (int i = 0; i < 4; ++i)
        #pragma unroll
        for (int b = 0; b < 8; ++b)
            #pragma unroll
            for (int m = 1; m < 64; m <<= 1)
                acc[i][b] += __shfl_xor(acc[i][b], m);

    __shared__ float part[4][32];
    if ((tid & 63) == 0) {
        #pragma unroll
        for (int i = 0; i < 4; ++i)
            #pragma unroll
            for (int b = 0; b < 8; ++b)
                part[w][i * 8 + b] = acc[i][b];
    }
    __syncthreads();
    if (tid < 32) {
        const int i = tid >> 3, b = tid & 7;
        const float v = part[0][tid] + part[1][tid] + part[2][tid] + part[3][tid];
        Out[b * ostr + fbase + i] = v + Bv[fbase + i];
    }
}

// ---------------- Kernel 2: RoPE (q in-place, k) + KV-cache scatter ----------------
__global__ __launch_bounds__(256) void rope_cache_kernel(
    float* __restrict__ q, const float* __restrict__ kraw, const float* __restrict__ vraw,
    const float* __restrict__ cosb, const float* __restrict__ sinb,
    const int* __restrict__ btab, const int* __restrict__ cs,
    float* __restrict__ kpool, float* __restrict__ vpool)
{
    const int b = blockIdx.x >> 2;
    const int qtr = blockIdx.x & 3;
    const int tid = threadIdx.x;

    for (int i = tid; i < 448; i += 256) {
        const int h = qtr * 7 + (i >> 6), dp = i & 63;
        float* base = q + (size_t)b * H + h * HD;
        const float x1 = base[dp], x2 = base[dp + 64];
        const float c1 = cosb[b * HD + dp],      s1 = sinb[b * HD + dp];
        const float c2 = cosb[b * HD + dp + 64], s2 = sinb[b * HD + dp + 64];
        base[dp]      = x1 * c1 - x2 * s1;
        base[dp + 64] = x2 * c2 + x1 * s2;
    }
    const int r = b * KVH + qtr;
    const int pos = cs[r] - 1;
    const int pb = btab[r * MB + (pos >> 8)];
    const int off = pos & 255;
    if (tid < 64) {
        const int dp = tid;
        const float* kb_ = kraw + (size_t)r * HD;
        const float x1 = kb_[dp], x2 = kb_[dp + 64];
        const float c1 = cosb[b * HD + dp],      s1 = sinb[b * HD + dp];
        const float c2 = cosb[b * HD + dp + 64], s2 = sinb[b * HD + dp + 64];
        float* dst = kpool + ((size_t)pb * BS + off) * HD;
        dst[dp]      = x1 * c1 - x2 * s1;
        dst[dp + 64] = x2 * c2 + x1 * s2;
    }
    if (tid < 128) {
        vpool[((size_t)pb * BS + off) * HD + tid] = vraw[(size_t)r * HD + tid];
    }
}

// ---------------- Kernel 3: flash-decode partials (2 waves per 64-token chunk) ----------------
// grid = (32 segs of 128 tokens, R rows), 256 threads = 4 waves.
// waves (0,1) -> chunk 2*seg, waves (2,3) -> chunk 2*seg+1. Each wave scores and
// PV-accumulates 32 tokens -> 2x the active waves vs the page-per-block version
// (8 waves/CU instead of 4: was latency-bound at 10% occupancy / 11% HBM).
// Per-chunk softmax (64 tokens) done by the half==0 wave; PV partials reduced
// across the wave pair via LDS. NCHUNK stays 64 -> partial traffic unchanged.
__global__ __launch_bounds__(256) void attn_partial_kernel(
    const float* __restrict__ q, const float* __restrict__ kpool, const float* __restrict__ vpool,
    const int* __restrict__ btab, const int* __restrict__ cs,
    float* __restrict__ pm, float* __restrict__ pl, float* __restrict__ po)
{
    const int seg = blockIdx.x;          // 128-token segment
    const int r = blockIdx.y;
    const int seqlen = cs[r];
    if ((seg << 7) >= seqlen) return;    // block-uniform exit (before any barrier)

    const int tid = threadIdx.x;
    const int w = tid >> 6;
    const int lane = tid & 63;
    const int cw = w >> 1;               // chunk within block (0/1)
    const int half = w & 1;              // which 32-token half of the chunk
    const int chunk = seg * 2 + cw;      // global chunk id 0..63
    const int c0 = chunk << 6;
    const int vt = min(64, max(0, seqlen - c0));   // valid tokens in chunk
    const int myvt = min(32, vt - half * 32);      // valid tokens in this wave's half (may be <=0)

    const int blk = btab[r * MB + (seg >> 1)];
    const int tok0 = ((seg & 1) << 7) + (cw << 6) + (half << 5);  // token offset in page
    const float* Kp = kpool + ((size_t)blk * BS + tok0) * HD;
    const float* Vp = vpool + ((size_t)blk * BS + tok0) * HD;

    __shared__ float s_p[2][GS][64];     // 3.5 KB: per-chunk score/p buffer
    __shared__ float s_o[2][GS][128];    // 7 KB: cross-wave PV reduce

    const int tl = lane >> 4;            // token within group of 4
    const int dg = lane & 15;            // dim-group: dims [dg*8, dg*8+8)

    // q fragments: 7 heads x 8 dims per lane
    float4 qa[GS], qb2[GS];
    #pragma unroll
    for (int g = 0; g < GS; ++g) {
        const float4* qp = (const float4*)(q + (size_t)(r * GS + g) * HD + dg * 8);
        qa[g] = qp[0]; qb2[g] = qp[1];
    }

    // ---- Phase A: scores for this wave's 32 tokens (16 lanes per token) ----
    if (myvt == 32) {
        #pragma unroll 4
        for (int i = 0; i < 8; ++i) {
            const int t = i * 4 + tl;
            const float4* kp4 = (const float4*)(Kp + (size_t)t * HD + dg * 8);
            const float4 ka = kp4[0], kb = kp4[1];
            #pragma unroll
            for (int g = 0; g < GS; ++g) {
                float v = dot4(qa[g], ka) + dot4(qb2[g], kb);
                v = red16(v);
                if (dg == 0) s_p[cw][g][half * 32 + t] = v * SCALE;
            }
        }
    } else if (myvt > 0) {
        const int nI = (myvt + 3) >> 2;
        for (int i = 0; i < nI; ++i) {
            const int t = i * 4 + tl;    // may exceed myvt (masked in softmax); stays in page
            const float4* kp4 = (const float4*)(Kp + (size_t)t * HD + dg * 8);
            const float4 ka = kp4[0], kb = kp4[1];
            #pragma unroll
            for (int g = 0; g < GS; ++g) {
                float v = dot4(qa[g], ka) + dot4(qb2[g], kb);
                v = red16(v);
                if (dg == 0) s_p[cw][g][half * 32 + t] = v * SCALE;
            }
        }
    }
    __syncthreads();

    // ---- Phase B: per-chunk softmax partial, by half==0 wave. Lane = token. ----
    if (half == 0 && vt > 0) {
        float mx[GS], lsum[GS];
        #pragma unroll
        for (int g = 0; g < GS; ++g) {
            float sv = (lane < vt) ? s_p[cw][g][lane] : -3.0e38f;
            float m_ = sv;
            #pragma unroll
            for (int m = 1; m < 64; m <<= 1) m_ = fmaxf(m_, __shfl_xor(m_, m));
            float p = (lane < vt) ? __expf(sv - m_) : 0.f;
            s_p[cw][g][lane] = p;        // all 64 slots defined after this (0 if invalid)
            float l_ = p;
            #pragma unroll
            for (int m = 1; m < 64; m <<= 1) l_ += __shfl_xor(l_, m);
            mx[g] = m_; lsum[g] = l_;
        }
        if (lane == 0) {
            const size_t pidx = (size_t)(r * NCHUNK + chunk) * GS;
            #pragma unroll
            for (int g = 0; g < GS; ++g) { pm[pidx + g] = mx[g]; pl[pidx + g] = lsum[g]; }
        }
    }
    __syncthreads();

    // ---- Phase C: PV partial over this wave's 32 tokens. Lane owns dims {2*lane, 2*lane+1}. ----
    float acc[GS][2];
    #pragma unroll
    for (int g = 0; g < GS; ++g) { acc[g][0] = 0.f; acc[g][1] = 0.f; }
    if (myvt > 0) {
        const int vt4 = (myvt + 3) & ~3;
        #pragma unroll 2
        for (int t = 0; t < vt4; t += 4) {
            float4 p4[GS];
            #pragma unroll
            for (int g = 0; g < GS; ++g) p4[g] = *(const float4*)&s_p[cw][g][half * 32 + t];
            #pragma unroll
            for (int k = 0; k < 4; ++k) {
                const float2 v2 = *(const float2*)(Vp + (size_t)(t + k) * HD + lane * 2);
                #pragma unroll
                for (int g = 0; g < GS; ++g) {
                    const float pk = (k == 0) ? p4[g].x : (k == 1) ? p4[g].y : (k == 2) ? p4[g].z : p4[g].w;
                    acc[g][0] = fmaf(pk, v2.x, acc[g][0]);
                    acc[g][1] = fmaf(pk, v2.y, acc[g][1]);
                }
            }
        }
    }
    // cross-wave reduce: half==1 publishes (zeros if its half was empty)
    if (half == 1) {
        #pragma unroll
        for (int g = 0; g < GS; ++g)
            *(float2*)&s_o[cw][g][lane * 2] = make_float2(acc[g][0], acc[g][1]);
    }
    __syncthreads();
    if (half == 0 && vt > 0) {
        const size_t pidx = (size_t)(r * NCHUNK + chunk) * GS;
        #pragma unroll
        for (int g = 0; g < GS; ++g) {
            const float2 other = *(const float2*)&s_o[cw][g][lane * 2];
            *(float2*)(po + (pidx + g) * HD + lane * 2) =
                make_float2(acc[g][0] + other.x, acc[g][1] + other.y);
        }
    }
}

// ---------------- Kernel 4: combine chunk partials (two-phase, no serial rescale) ----------------
// grid = R*GS blocks of 128. Stage 1 (wave 0, lane = chunk): M = max_c pm,
// w_c = exp(pm_c - M), L = sum w_c*pl_c -> LDS. Stage 2 (thread = dim):
// dependency-free weighted sum over chunks (loads pipeline freely).
__global__ __launch_bounds__(128) void combine_kernel(
    const float* __restrict__ pm, const float* __restrict__ pl, const float* __restrict__ po,
    const int* __restrict__ cs, float* __restrict__ att)
{
    const int bx = blockIdx.x;
    const int r = bx / GS, g = bx % GS;
    const int nc = (cs[r] + 63) >> 6;    // 1..64
    const int tid = threadIdx.x;

    __shared__ float w_s[64];
    __shared__ float L_s;

    if (tid < 64) {
        const int c = tid;
        float m = -3.0e38f, l = 0.f;
        if (c < nc) {
            const size_t idx = (size_t)(r * NCHUNK + c) * GS + g;
            m = pm[idx]; l = pl[idx];
        }
        float M = m;
        #pragma unroll
        for (int s = 1; s < 64; s <<= 1) M = fmaxf(M, __shfl_xor(M, s));
        const float wgt = __expf(m - M);           // 0 for inactive lanes
        float L = l * wgt;
        #pragma unroll
        for (int s = 1; s < 64; s <<= 1) L += __shfl_xor(L, s);
        w_s[c] = wgt;
        if (c == 0) L_s = L;
    }
    __syncthreads();

    const int d = tid;                   // 0..127
    const size_t base = (size_t)r * NCHUNK * GS + g;
    float acc = 0.f;
    int c = 0;
    for (; c + 4 <= nc; c += 4) {
        const float a0 = po[(base + (size_t)(c + 0) * GS) * HD + d];
        const float a1 = po[(base + (size_t)(c + 1) * GS) * HD + d];
        const float a2 = po[(base + (size_t)(c + 2) * GS) * HD + d];
        const float a3 = po[(base + (size_t)(c + 3) * GS) * HD + d];
        acc += w_s[c] * a0 + w_s[c + 1] * a1 + w_s[c + 2] * a2 + w_s[c + 3] * a3;
    }
    for (; c < nc; ++c) {
        acc += w_s[c] * po[(base + (size_t)c * GS) * HD + d];
    }
    att[(size_t)(r * GS + g) * HD + d] = acc / L_s;
}

// ---------------- Kernel 5: O projection GEMV ----------------
__global__ __launch_bounds__(256) void oproj_kernel(
    const float* __restrict__ att, const float* __restrict__ ow, float* __restrict__ out)
{
    const int blk = blockIdx.x;
    const int tid = threadIdx.x;
    const int w = tid >> 6;
    const int f0 = blk * 4;

    const float4* wr0 = (const float4*)(ow + (size_t)(f0 + 0) * H);
    const float4* wr1 = (const float4*)(ow + (size_t)(f0 + 1) * H);
    const float4* wr2 = (const float4*)(ow + (size_t)(f0 + 2) * H);
    const float4* wr3 = (const float4*)(ow + (size_t)(f0 + 3) * H);
    const float4* a4 = (const float4*)att;

    float acc[4][8];
    #pragma unroll
    for (int i = 0; i < 4; ++i)
        #pragma unroll
        for (int b = 0; b < 8; ++b) acc[i][b] = 0.f;

    #pragma unroll
    for (int k = 0; k < 4; ++k) {
        const int c = tid + k * 256;
        if (c < 896) {
            float4 w0 = wr0[c], w1 = wr1[c], w2 = wr2[c], w3 = wr3[c];
            float4 hb[8];
            #pragma unroll
            for (int b = 0; b < 8; ++b) hb[b] = a4[b * 896 + c];
            #pragma unroll
            for (int b = 0; b < 8; ++b) {
                acc[0][b] += dot4(w0, hb[b]);
                acc[1][b] += dot4(w1, hb[b]);
                acc[2][b] += dot4(w2, hb[b]);
                acc[3][b] += dot4(w3, hb[b]);
            }
        }
    }
    #pragma unroll
    for (int i = 0; i < 4; ++i)
        #pragma unroll
        for (int b = 0; b < 8; ++b)
            #pragma unroll
            for (int m = 1; m < 64; m <<= 1)
                acc[i][b] += __shfl_xor(acc[i][b], m);

    __shared__ float part[4][32];
    if ((tid & 63) == 0) {
        #pragma unroll
        for (int i = 0; i < 4; ++i)
            #pragma unroll
            for (int b = 0; b < 8; ++b)
                part[w][i * 8 + b] = acc[i][b];
    }
    __syncthreads();
    if (tid < 32) {
        const int i = tid >> 3, b = tid & 7;
        out[b * H + f0 + i] = part[0][tid] + part[1][tid] + part[2][tid] + part[3][tid];
    }
}

extern "C" void kernel_launch(void* const* d_in, const int* in_sizes, int n_in,
                              void* d_out, int out_size, void* d_ws, size_t ws_size,
                              hipStream_t stream) {
    (void)in_sizes; (void)n_in; (void)out_size; (void)ws_size;
    const float* hid  = (const float*)d_in[0];
    const float* cosb = (const float*)d_in[1];
    const float* sinb = (const float*)d_in[2];
    const float* qw   = (const float*)d_in[3];
    const float* qb   = (const float*)d_in[4];
    const float* kw   = (const float*)d_in[5];
    const float* kb   = (const float*)d_in[6];
    const float* vw   = (const float*)d_in[7];
    const float* vb   = (const float*)d_in[8];
    const float* ow   = (const float*)d_in[9];
    float* kpool      = (float*)d_in[10];
    float* vpool      = (float*)d_in[11];
    const int* btab   = (const int*)d_in[12];
    const int* cs     = (const int*)d_in[13];

    float* ws   = (float*)d_ws;
    float* q    = ws;             // 28672
    float* kraw = q + 28672;      // 4096
    float* vraw = kraw + 4096;    // 4096
    float* att  = vraw + 4096;    // 28672
    float* pm   = att + 28672;    // R*NCHUNK*GS = 14336
    float* pl   = pm + 14336;     // 14336
    float* po   = pl + 14336;     // R*NCHUNK*GS*HD = 1835008 (~7.3 MB)

    hipLaunchKernelGGL(qkv_kernel, dim3(1152), dim3(256), 0, stream,
                       hid, qw, qb, kw, kb, vw, vb, q, kraw, vraw);
    hipLaunchKernelGGL(rope_cache_kernel, dim3(32), dim3(256), 0, stream,
                       q, kraw, vraw, cosb, sinb, btab, cs, kpool, vpool);
    hipLaunchKernelGGL(attn_partial_kernel, dim3(32, R), dim3(256), 0, stream,
                       q, kpool, vpool, btab, cs, pm, pl, po);
    hipLaunchKernelGGL(combine_kernel, dim3(R * GS), dim3(128), 0, stream,
                       pm, pl, po, cs, att);
    hipLaunchKernelGGL(oproj_kernel, dim3(896), dim3(256), 0, stream,
                       att, ow, (float*)d_out);
}